// Round 12
// baseline (464.840 us; speedup 1.0000x reference)
//
#include <hip/hip_runtime.h>
#include <hip/hip_bf16.h>

#define N_NODES 50000
#define N_EDGES 250000
#define DIN_ 256
#define DOUT_ 256
#define OH_ 16
#define KF_ 288   // 256 (h) + 16 (degrees) + 16 zero-pad
#define NBLK_G ((N_NODES + 63) / 64)        // 782
#define SCAN_TOT (2 * N_NODES)              // 100000
#define SCAN_NB ((SCAN_TOT + 255) / 256)    // 391
#define NB_CONV ((N_NODES * DIN_ / 8) / 256)        // 6250
#define NB_PREP ((DOUT_ * KF_ + 255) / 256)         // 288
#define NB_HIST ((N_EDGES + 255) / 256)             // 977
#define NODE_BLK 16
#define NBLK_NODE (N_NODES / NODE_BLK)              // 3125 (exact)

typedef short short8 __attribute__((ext_vector_type(8)));
typedef float f32x4 __attribute__((ext_vector_type(4)));

__device__ __forceinline__ unsigned short f2bf(float f) {
    unsigned u = __builtin_bit_cast(unsigned, f);
    return (unsigned short)((u + 0x7fffu + ((u >> 16) & 1u)) >> 16);
}

__device__ __forceinline__ float bf2f(unsigned v) {
    return __builtin_bit_cast(float, v << 16);
}

__device__ __forceinline__ uint4 pack8(float f0, float f1, float f2, float f3,
                                       float f4, float f5, float f6, float f7) {
    uint4 u;
    u.x = (unsigned)f2bf(f0) | ((unsigned)f2bf(f1) << 16);
    u.y = (unsigned)f2bf(f2) | ((unsigned)f2bf(f3) << 16);
    u.z = (unsigned)f2bf(f4) | ((unsigned)f2bf(f5) << 16);
    u.w = (unsigned)f2bf(f6) | ((unsigned)f2bf(f7) << 16);
    return u;
}

__device__ __forceinline__ float fast_rcp(float x) {
#if __has_builtin(__builtin_amdgcn_rcpf)
    return __builtin_amdgcn_rcpf(x);
#else
    return 1.0f / x;
#endif
}

// async global -> LDS, 16 bytes per lane (dest = wave-uniform base + lane*16)
__device__ __forceinline__ void gl_lds16(const void* g, void* l) {
    __builtin_amdgcn_global_load_lds(
        (const __attribute__((address_space(1))) unsigned int*)g,
        (__attribute__((address_space(3))) unsigned int*)l, 16, 0, 0);
}

// ---------- fused prep: conv_h + prep_weights + hist ----------
__global__ void fused_prep(const float* __restrict__ h, unsigned short* __restrict__ hbf,
                           const float* __restrict__ W_lin,
                           const float* __restrict__ W_k0,
                           const float* __restrict__ W_k1,
                           unsigned short* __restrict__ WT_lin,
                           unsigned short* __restrict__ WT_k0,
                           unsigned short* __restrict__ WT_k1,
                           const int* __restrict__ sc0, const int* __restrict__ sc1,
                           int* __restrict__ hist) {
    int bx = blockIdx.x;
    if (bx < NB_CONV) {
        int idx = bx * 256 + threadIdx.x;
        const f32x4* s = (const f32x4*)(h + (size_t)idx * 8);
        f32x4 a = s[0], b = s[1];
        ((uint4*)hbf)[idx] = pack8(a[0], a[1], a[2], a[3], b[0], b[1], b[2], b[3]);
    } else if (bx < NB_CONV + NB_PREP) {
        int idx = (bx - NB_CONV) * 256 + threadIdx.x;
        if (idx < DOUT_ * DIN_) {
            int n = idx >> 8, k = idx & 255;
            WT_lin[idx] = f2bf(W_lin[k * DOUT_ + n]);
        }
        if (idx < DOUT_ * KF_) {
            int n = idx / KF_, k = idx - n * KF_;
            float v0 = 0.f, v1 = 0.f;
            if (k < DIN_ + OH_) {
                v0 = W_k0[k * DOUT_ + n];
                v1 = W_k1[k * DOUT_ + n];
            }
            WT_k0[idx] = f2bf(v0);
            WT_k1[idx] = f2bf(v1);
        }
    } else {
        int e = (bx - NB_CONV - NB_PREP) * 256 + threadIdx.x;
        if (e < N_EDGES) {
            atomicAdd(&hist[sc0[e]], 1);
            atomicAdd(&hist[N_NODES + sc1[e]], 1);
        }
    }
}

// ---------- scan passes ----------
__global__ void scan_pass1(const int* __restrict__ hist, int* __restrict__ partials) {
    __shared__ int sdata[256];
    int gid = blockIdx.x * 256 + threadIdx.x;
    sdata[threadIdx.x] = (gid < SCAN_TOT) ? hist[gid] : 0;
    __syncthreads();
    for (int d = 128; d > 0; d >>= 1) {
        if (threadIdx.x < d) sdata[threadIdx.x] += sdata[threadIdx.x + d];
        __syncthreads();
    }
    if (threadIdx.x == 0) partials[blockIdx.x] = sdata[0];
}

__global__ __launch_bounds__(512) void scan_pass2(int* __restrict__ partials) {
    __shared__ int s[512];
    int t = threadIdx.x;
    s[t] = (t < SCAN_NB) ? partials[t] : 0;
    __syncthreads();
    for (int d = 1; d < 512; d <<= 1) {
        int add = (t >= d) ? s[t - d] : 0;
        __syncthreads();
        s[t] += add;
        __syncthreads();
    }
    if (t < SCAN_NB) partials[t] = (t == 0) ? 0 : s[t - 1];   // exclusive
}

__global__ void scan_pass3(const int* __restrict__ hist, const int* __restrict__ partials,
                           int* __restrict__ offs) {
    __shared__ int s[256];
    int gid = blockIdx.x * 256 + threadIdx.x;
    int t = threadIdx.x;
    int v = (gid < SCAN_TOT) ? hist[gid] : 0;
    s[t] = v;
    __syncthreads();
    for (int d = 1; d < 256; d <<= 1) {
        int add = (t >= d) ? s[t - d] : 0;
        __syncthreads();
        s[t] += add;
        __syncthreads();
    }
    if (gid < SCAN_TOT) offs[gid] = partials[blockIdx.x] + s[t] - v;  // exclusive
}

// ---------- fused: rank + 3 linear GEMMs ----------
__global__ __launch_bounds__(256) void rank_lin(const int* __restrict__ sc0,
                                                const int* __restrict__ sc1,
                                                int* __restrict__ offs,
                                                int* __restrict__ order,
                                                int* __restrict__ keys,
                                                const unsigned short* __restrict__ hbf,
                                                const unsigned short* __restrict__ WT_lin,
                                                const unsigned short* __restrict__ WTk0,
                                                const unsigned short* __restrict__ WTk1,
                                                const float* __restrict__ b_lin,
                                                const float* __restrict__ bk0,
                                                const float* __restrict__ bk1,
                                                float* __restrict__ out,
                                                unsigned short* __restrict__ G0,
                                                unsigned short* __restrict__ G1) {
    if (blockIdx.x >= 3 * NBLK_G) {
        int e = (blockIdx.x - 3 * NBLK_G) * 256 + threadIdx.x;
        if (e < N_EDGES) {
            int k0 = sc0[e];
            int p = atomicAdd(&offs[k0], 1);
            order[p] = e; keys[p] = k0;
            int k1 = sc1[e];
            int q = atomicAdd(&offs[N_NODES + k1], 1);
            order[q] = e; keys[q] = k1;
        }
        return;
    }
    __shared__ unsigned short Alds[2][64][32];
    __shared__ unsigned short Blds[2][256][32];
    __shared__ float bias_lds[256];
    int kb = blockIdx.x / NBLK_G;
    int bx = blockIdx.x - kb * NBLK_G;
    const unsigned short* WT; const float* bias; int stride;
    if (kb == 0)      { WT = WTk0;   bias = bk0;   stride = KF_; }
    else if (kb == 1) { WT = WTk1;   bias = bk1;   stride = KF_; }
    else              { WT = WT_lin; bias = b_lin; stride = DIN_; }

    int tid = threadIdx.x;
    int w = tid >> 6, ln = tid & 63, l15 = ln & 15;
    int row0 = bx * 64;
    bias_lds[tid] = bias[tid];

    int ar = row0 + w * 16 + (ln >> 2);
    if (ar >= N_NODES) ar = N_NODES - 1;
    int qs = (ln & 3) ^ ((ln >> 3) & 3);
    const unsigned short* asrc = hbf + (size_t)ar * DIN_ + qs * 8;
    int brow = w * 64;
    int swz = ((ln >> 4) ^ ((l15 >> 1) & 3)) * 8;

    f32x4 acc[16];
#pragma unroll
    for (int j = 0; j < 16; ++j) acc[j] = (f32x4)(0.f);

    gl_lds16(asrc, &Alds[0][w * 16][0]);
#pragma unroll
    for (int i = 0; i < 4; ++i) {
        int n = brow + i * 16 + (ln >> 2);
        gl_lds16(WT + (size_t)n * stride + qs * 8, &Blds[0][brow + i * 16][0]);
    }
    __syncthreads();

    int buf = 0;
    for (int kk = 0; kk < 8; ++kk) {
        if (kk < 7) {
            gl_lds16(asrc + (kk + 1) * 32, &Alds[buf ^ 1][w * 16][0]);
#pragma unroll
            for (int i = 0; i < 4; ++i) {
                int n = brow + i * 16 + (ln >> 2);
                gl_lds16(WT + (size_t)n * stride + (kk + 1) * 32 + qs * 8,
                         &Blds[buf ^ 1][brow + i * 16][0]);
            }
        }
        short8 af = *(const short8*)&Alds[buf][w * 16 + l15][swz];
#pragma unroll
        for (int j = 0; j < 16; ++j) {
            short8 bf = *(const short8*)&Blds[buf][j * 16 + l15][swz];
            acc[j] = __builtin_amdgcn_mfma_f32_16x16x32_bf16(af, bf, acc[j], 0, 0, 0);
        }
        __syncthreads();
        buf ^= 1;
    }

    int rbase = row0 + w * 16 + ((ln >> 4) << 2);
    unsigned short* G = (kb == 0) ? G0 : G1;
#pragma unroll
    for (int j = 0; j < 16; ++j) {
        int n = j * 16 + l15;
        float bv = bias_lds[n];
#pragma unroll
        for (int i = 0; i < 4; ++i) {
            int rr = rbase + i;
            if (rr < N_NODES) {
                float v = acc[j][i] + bv;
                if (kb == 2) out[(size_t)rr * DOUT_ + n] = v;
                else         G[(size_t)rr * DOUT_ + n] = f2bf(v);
            }
        }
    }
}

// Node-major edge kernel: block owns 16 output nodes, both keys. CSR slices from offs
// (post-rank end-pointers). Runs accumulate into LDS (ds_add_f32); out written once,
// plain coalesced, ZERO global atomics.
__global__ __launch_bounds__(256, 4) void edge_node(const unsigned short* __restrict__ Gk0,
                                                    const unsigned short* __restrict__ Gk1,
                                                    const int* __restrict__ pairs0,
                                                    const int* __restrict__ pairs1,
                                                    const float* __restrict__ deg0,
                                                    const float* __restrict__ deg1,
                                                    const int* __restrict__ order_g,  // [2E]
                                                    const int* __restrict__ keys_g,   // [2E]
                                                    const int* __restrict__ offs_v,   // [2N] end pos
                                                    const unsigned short* __restrict__ WT0,
                                                    const unsigned short* __restrict__ WT1,
                                                    const float* __restrict__ eps0,
                                                    const float* __restrict__ eps1,
                                                    float* __restrict__ out) {
    __shared__ float accL[NODE_BLK][260];      // 16.6 KB per-node accumulator (256 cols)
    __shared__ unsigned int Dlds[32][132];     // 16.9 KB t-packed D, one 128-col phase
    __shared__ int el_c[32], tg_c[32], p0_c[32], p1_c[32];

    int n0 = blockIdx.x * NODE_BLK;
    int tid = threadIdx.x, w = tid >> 6, ln = tid & 63, l15 = ln & 15, ks = ln >> 4;

    for (int i = tid; i < NODE_BLK * 260; i += 256) (&accL[0][0])[i] = 0.f;

    for (int kb = 0; kb < 2; ++kb) {
        const unsigned short* G = kb ? Gk1 : Gk0;
        const int* pairs = kb ? pairs1 : pairs0;
        const float* degrees = kb ? deg1 : deg0;
        const unsigned short* WT = kb ? WT1 : WT0;
        float epv = 1.0f + (kb ? eps1[0] : eps0[0]);
        int i0 = kb * N_NODES + n0;
        int gs = (i0 == 0) ? 0 : offs_v[i0 - 1];
        int ge = offs_v[i0 + NODE_BLK - 1];

        for (int cs = gs; cs < ge; cs += 32) {
            __syncthreads();   // protect el_c/Dlds reuse (also covers accL zero-init)
            if (tid < 32) {
                int s = cs + tid;
                int e;
                if (s < ge) {
                    e = __builtin_nontemporal_load(order_g + s);
                    tg_c[tid] = __builtin_nontemporal_load(keys_g + s) - n0;
                } else {
                    e = __builtin_nontemporal_load(order_g + (ge - 1));
                    tg_c[tid] = -1;
                }
                el_c[tid] = e;
                p0_c[tid] = pairs[e];
                p1_c[tid] = pairs[N_EDGES + e];
            }
            __syncthreads();

            // ---- all G gathers for this chunk (8 slots x 2 pairs x 2 phases) ----
            unsigned int gv[4][8];
#pragma unroll
            for (int r = 0; r < 8; ++r) {
                int slot = w * 8 + r;
                const unsigned int* b0 = (const unsigned int*)(G + (size_t)p0_c[slot] * DOUT_) + ln;
                const unsigned int* b1 = (const unsigned int*)(G + (size_t)p1_c[slot] * DOUT_) + ln;
                gv[0][r] = b0[0];      // phase0 pair0
                gv[1][r] = b1[0];      // phase0 pair1
                gv[2][r] = b0[64];     // phase1 pair0
                gv[3][r] = b1[64];     // phase1 pair1
            }
            asm volatile("" ::: "memory");

            // ---- A-frags (degrees), both 16-slot row-tiles ----
            short8 afr[2][2];
#pragma unroll
            for (int rt = 0; rt < 2; ++rt) {
                f32x4 xa = (f32x4)(0.f), xb = xa, ya = xa, yb = xa;
                int eA = el_c[rt * 16 + l15];
                if (ks < 2) {
                    const f32x4* s0 = (const f32x4*)(degrees + (size_t)eA * OH_ + ks * 8);
                    const f32x4* s1 = (const f32x4*)(degrees + ((size_t)N_EDGES + eA) * OH_ + ks * 8);
                    xa = __builtin_nontemporal_load(s0);
                    xb = __builtin_nontemporal_load(s0 + 1);
                    ya = __builtin_nontemporal_load(s1);
                    yb = __builtin_nontemporal_load(s1 + 1);
                }
                afr[rt][0] = __builtin_bit_cast(short8, pack8(xa[0], xa[1], xa[2], xa[3],
                                                              xb[0], xb[1], xb[2], xb[3]));
                afr[rt][1] = __builtin_bit_cast(short8, pack8(ya[0], ya[1], ya[2], ya[3],
                                                              yb[0], yb[1], yb[2], yb[3]));
                if (ks >= 2) { afr[rt][0] = (short8)0; afr[rt][1] = (short8)0; }
            }

#pragma unroll
            for (int p = 0; p < 2; ++p) {
                // MFMA: this wave covers col-tiles (2w, 2w+1) of the phase, both row-tiles
#pragma unroll
                for (int jj = 0; jj < 2; ++jj) {
                    int n = p * 128 + (w * 2 + jj) * 16 + l15;
                    short8 bf = (short8)0;
                    if (ks < 2) bf = *(const short8*)(WT + (size_t)n * KF_ + 256 + ks * 8);
#pragma unroll
                    for (int rt = 0; rt < 2; ++rt) {
                        f32x4 a0 = (f32x4)(0.f), a1 = (f32x4)(0.f);
                        a0 = __builtin_amdgcn_mfma_f32_16x16x32_bf16(afr[rt][0], bf, a0, 0, 0, 0);
                        a1 = __builtin_amdgcn_mfma_f32_16x16x32_bf16(afr[rt][1], bf, a1, 0, 0, 0);
#pragma unroll
                        for (int i = 0; i < 4; ++i)
                            Dlds[rt * 16 + ks * 4 + i][(w * 2 + jj) * 16 + l15] =
                                (unsigned)f2bf(a0[i]) | ((unsigned)f2bf(a1[i]) << 16);
                    }
                }
                __syncthreads();   // D visible

                // reduce: this wave's 8 slots, cols p*128 + {2ln, 2ln+1}
                int runkey = -1; float rs0 = 0.f, rs1 = 0.f;
#pragma unroll
                for (int r = 0; r < 8; ++r) {
                    int slot = w * 8 + r;
                    uint2 dp = *(const uint2*)&Dlds[slot][2 * ln];
                    unsigned g0u = gv[2 * p][r], g1u = gv[2 * p + 1][r];
                    float la0 = bf2f(g0u & 0xffffu) + bf2f(dp.x & 0xffffu);
                    float la1 = bf2f(g1u & 0xffffu) + bf2f(dp.x >> 16);
                    float ha0 = bf2f(g0u >> 16) + bf2f(dp.y & 0xffffu);
                    float ha1 = bf2f(g1u >> 16) + bf2f(dp.y >> 16);
                    float v0 = fast_rcp((1.f + __expf(-la0)) * (1.f + __expf(-la1)));
                    float v1 = fast_rcp((1.f + __expf(-ha0)) * (1.f + __expf(-ha1)));
                    int k = tg_c[slot];
                    if (k != runkey) {
                        if (runkey >= 0) {
                            atomicAdd(&accL[runkey][p * 128 + 2 * ln], epv * rs0);
                            atomicAdd(&accL[runkey][p * 128 + 2 * ln + 1], epv * rs1);
                        }
                        runkey = k; rs0 = v0; rs1 = v1;
                    } else { rs0 += v0; rs1 += v1; }
                }
                if (runkey >= 0) {
                    atomicAdd(&accL[runkey][p * 128 + 2 * ln], epv * rs0);
                    atomicAdd(&accL[runkey][p * 128 + 2 * ln + 1], epv * rs1);
                }
                __syncthreads();   // before Dlds overwrite / next chunk
            }
        }
    }
    __syncthreads();
    // single-writer final store: out = main (already there) + accumulated edge terms
#pragma unroll
    for (int i = 0; i < NODE_BLK; ++i) {
        size_t idx = (size_t)(n0 + i) * DOUT_ + tid;
        out[idx] = out[idx] + accL[i][tid];
    }
}

extern "C" void kernel_launch(void* const* d_in, const int* in_sizes, int n_in,
                              void* d_out, int out_size, void* d_ws, size_t ws_size,
                              hipStream_t stream) {
    const float* h        = (const float*)d_in[0];
    const int*   pairs_k0 = (const int*)d_in[1];
    const int*   pairs_k1 = (const int*)d_in[2];
    const float* deg_k0   = (const float*)d_in[3];
    const float* deg_k1   = (const float*)d_in[4];
    const int*   sc_k0    = (const int*)d_in[5];
    const int*   sc_k1    = (const int*)d_in[6];
    const float* W_lin    = (const float*)d_in[7];
    const float* b_lin    = (const float*)d_in[8];
    const float* W_k0     = (const float*)d_in[9];
    const float* b_k0     = (const float*)d_in[10];
    const float* W_k1     = (const float*)d_in[11];
    const float* b_k1     = (const float*)d_in[12];
    const float* eps_k0   = (const float*)d_in[13];
    const float* eps_k1   = (const float*)d_in[14];
    float* out = (float*)d_out;

    size_t ush_elems = (size_t)DOUT_ * DIN_ + 2 * (size_t)DOUT_ * KF_
                     + 3 * (size_t)N_NODES * DIN_;          // h_bf + G0 + G1
    size_t int_elems = 2 * (size_t)N_NODES * 2 + 2 * (size_t)N_EDGES * 2 + 512;
    size_t need = ush_elems * sizeof(unsigned short) + int_elems * sizeof(int);
    if (ws_size < need) return;  // fail loudly in validation

    unsigned short* WT_lin = (unsigned short*)d_ws;
    unsigned short* WT_k0  = WT_lin + DOUT_ * DIN_;
    unsigned short* WT_k1  = WT_k0 + DOUT_ * KF_;
    unsigned short* h_bf   = WT_k1 + DOUT_ * KF_;
    unsigned short* G0     = h_bf + (size_t)N_NODES * DIN_;
    unsigned short* G1     = G0 + (size_t)N_NODES * DIN_;
    int* hist     = (int*)(G1 + (size_t)N_NODES * DIN_);
    int* offs     = hist + 2 * N_NODES;
    int* order    = offs + 2 * N_NODES;     // [2*E]
    int* keys     = order + 2 * N_EDGES;    // [2*E]
    int* partials = keys + 2 * N_EDGES;     // [512]

    hipMemsetAsync(hist, 0, 2 * N_NODES * sizeof(int), stream);
    fused_prep<<<NB_CONV + NB_PREP + NB_HIST, 256, 0, stream>>>(
        h, h_bf, W_lin, W_k0, W_k1, WT_lin, WT_k0, WT_k1, sc_k0, sc_k1, hist);
    scan_pass1<<<SCAN_NB, 256, 0, stream>>>(hist, partials);
    scan_pass2<<<1, 512, 0, stream>>>(partials);
    scan_pass3<<<SCAN_NB, 256, 0, stream>>>(hist, partials, offs);
    rank_lin<<<3 * NBLK_G + NB_HIST, 256, 0, stream>>>(
        sc_k0, sc_k1, offs, order, keys, h_bf, WT_lin, WT_k0, WT_k1,
        b_lin, b_k0, b_k1, out, G0, G1);
    edge_node<<<NBLK_NODE, 256, 0, stream>>>(G0, G1, pairs_k0, pairs_k1,
                                             deg_k0, deg_k1, order, keys, offs,
                                             WT_k0, WT_k1, eps_k0, eps_k1, out);
}

// Round 13
// 424.869 us; speedup vs baseline: 1.0941x; 1.0941x over previous
//
#include <hip/hip_runtime.h>
#include <hip/hip_bf16.h>

#define N_NODES 50000
#define N_EDGES 250000
#define DIN_ 256
#define DOUT_ 256
#define OH_ 16
#define KF_ 288   // 256 (h) + 16 (degrees) + 16 zero-pad
#define NBLK_EDGE ((N_EDGES + 63) / 64)     // 3907
#define NBLK_G ((N_NODES + 63) / 64)        // 782
#define SCAN_TOT (2 * N_NODES)              // 100000
#define SCAN_NB ((SCAN_TOT + 255) / 256)    // 391
#define NB_CONV ((N_NODES * DIN_ / 8) / 256)        // 6250
#define NB_PREP ((DOUT_ * KF_ + 255) / 256)         // 288
#define NB_HIST ((N_EDGES + 255) / 256)             // 977
#define LOG2E 1.44269504088896340736f

typedef short short8 __attribute__((ext_vector_type(8)));
typedef float f32x4 __attribute__((ext_vector_type(4)));

__device__ __forceinline__ unsigned short f2bf(float f) {
    unsigned u = __builtin_bit_cast(unsigned, f);
    return (unsigned short)((u + 0x7fffu + ((u >> 16) & 1u)) >> 16);
}

__device__ __forceinline__ float bf2f(unsigned v) {
    return __builtin_bit_cast(float, v << 16);
}

__device__ __forceinline__ uint4 pack8(float f0, float f1, float f2, float f3,
                                       float f4, float f5, float f6, float f7) {
    uint4 u;
    u.x = (unsigned)f2bf(f0) | ((unsigned)f2bf(f1) << 16);
    u.y = (unsigned)f2bf(f2) | ((unsigned)f2bf(f3) << 16);
    u.z = (unsigned)f2bf(f4) | ((unsigned)f2bf(f5) << 16);
    u.w = (unsigned)f2bf(f6) | ((unsigned)f2bf(f7) << 16);
    return u;
}

__device__ __forceinline__ float fast_rcp(float x) {
#if __has_builtin(__builtin_amdgcn_rcpf)
    return __builtin_amdgcn_rcpf(x);
#else
    return 1.0f / x;
#endif
}

__device__ __forceinline__ float fast_exp2(float x) {
#if __has_builtin(__builtin_amdgcn_exp2f)
    return __builtin_amdgcn_exp2f(x);
#else
    return exp2f(x);
#endif
}

// async global -> LDS, 16 bytes per lane (dest = wave-uniform base + lane*16)
__device__ __forceinline__ void gl_lds16(const void* g, void* l) {
    __builtin_amdgcn_global_load_lds(
        (const __attribute__((address_space(1))) unsigned int*)g,
        (__attribute__((address_space(3))) unsigned int*)l, 16, 0, 0);
}

// ---------- fused prep: conv_h + prep_weights + hist ----------
// Deg-weight rows (k >= 256) pre-scaled by log2(e) so edge logits are exp2-ready.
__global__ void fused_prep(const float* __restrict__ h, unsigned short* __restrict__ hbf,
                           const float* __restrict__ W_lin,
                           const float* __restrict__ W_k0,
                           const float* __restrict__ W_k1,
                           unsigned short* __restrict__ WT_lin,
                           unsigned short* __restrict__ WT_k0,
                           unsigned short* __restrict__ WT_k1,
                           const int* __restrict__ sc0, const int* __restrict__ sc1,
                           int* __restrict__ hist) {
    int bx = blockIdx.x;
    if (bx < NB_CONV) {
        int idx = bx * 256 + threadIdx.x;
        const f32x4* s = (const f32x4*)(h + (size_t)idx * 8);
        f32x4 a = s[0], b = s[1];
        ((uint4*)hbf)[idx] = pack8(a[0], a[1], a[2], a[3], b[0], b[1], b[2], b[3]);
    } else if (bx < NB_CONV + NB_PREP) {
        int idx = (bx - NB_CONV) * 256 + threadIdx.x;
        if (idx < DOUT_ * DIN_) {
            int n = idx >> 8, k = idx & 255;
            WT_lin[idx] = f2bf(W_lin[k * DOUT_ + n]);
        }
        if (idx < DOUT_ * KF_) {
            int n = idx / KF_, k = idx - n * KF_;
            float v0 = 0.f, v1 = 0.f;
            if (k < DIN_ + OH_) {
                v0 = W_k0[k * DOUT_ + n];
                v1 = W_k1[k * DOUT_ + n];
                if (k >= DIN_) { v0 *= LOG2E; v1 *= LOG2E; }   // deg rows exp2-scaled
            }
            WT_k0[idx] = f2bf(v0);
            WT_k1[idx] = f2bf(v1);
        }
    } else {
        int e = (bx - NB_CONV - NB_PREP) * 256 + threadIdx.x;
        if (e < N_EDGES) {
            atomicAdd(&hist[sc0[e]], 1);
            atomicAdd(&hist[N_NODES + sc1[e]], 1);
        }
    }
}

// ---------- scan passes ----------
__global__ void scan_pass1(const int* __restrict__ hist, int* __restrict__ partials) {
    __shared__ int sdata[256];
    int gid = blockIdx.x * 256 + threadIdx.x;
    sdata[threadIdx.x] = (gid < SCAN_TOT) ? hist[gid] : 0;
    __syncthreads();
    for (int d = 128; d > 0; d >>= 1) {
        if (threadIdx.x < d) sdata[threadIdx.x] += sdata[threadIdx.x + d];
        __syncthreads();
    }
    if (threadIdx.x == 0) partials[blockIdx.x] = sdata[0];
}

__global__ __launch_bounds__(512) void scan_pass2(int* __restrict__ partials) {
    __shared__ int s[512];
    int t = threadIdx.x;
    s[t] = (t < SCAN_NB) ? partials[t] : 0;
    __syncthreads();
    for (int d = 1; d < 512; d <<= 1) {
        int add = (t >= d) ? s[t - d] : 0;
        __syncthreads();
        s[t] += add;
        __syncthreads();
    }
    if (t < SCAN_NB) partials[t] = (t == 0) ? 0 : s[t - 1];   // exclusive
}

__global__ void scan_pass3(const int* __restrict__ hist, const int* __restrict__ partials,
                           int* __restrict__ offs) {
    __shared__ int s[256];
    int gid = blockIdx.x * 256 + threadIdx.x;
    int t = threadIdx.x;
    int v = (gid < SCAN_TOT) ? hist[gid] : 0;
    s[t] = v;
    __syncthreads();
    for (int d = 1; d < 256; d <<= 1) {
        int add = (t >= d) ? s[t - d] : 0;
        __syncthreads();
        s[t] += add;
        __syncthreads();
    }
    if (gid < SCAN_TOT) offs[gid] = partials[blockIdx.x] + s[t] - v;  // exclusive
}

// ---------- fused: rank + 3 linear GEMMs ----------
// G epilogue pre-scales by log2(e) (bias folded first) for the exp2 edge path.
__global__ __launch_bounds__(256) void rank_lin(const int* __restrict__ sc0,
                                                const int* __restrict__ sc1,
                                                int* __restrict__ offs,
                                                int* __restrict__ order,
                                                int* __restrict__ keys,
                                                const unsigned short* __restrict__ hbf,
                                                const unsigned short* __restrict__ WT_lin,
                                                const unsigned short* __restrict__ WTk0,
                                                const unsigned short* __restrict__ WTk1,
                                                const float* __restrict__ b_lin,
                                                const float* __restrict__ bk0,
                                                const float* __restrict__ bk1,
                                                float* __restrict__ out,
                                                unsigned short* __restrict__ G0,
                                                unsigned short* __restrict__ G1) {
    if (blockIdx.x >= 3 * NBLK_G) {
        int e = (blockIdx.x - 3 * NBLK_G) * 256 + threadIdx.x;
        if (e < N_EDGES) {
            int k0 = sc0[e];
            int p = atomicAdd(&offs[k0], 1);
            order[p] = e; keys[p] = k0;
            int k1 = sc1[e];
            int q = atomicAdd(&offs[N_NODES + k1], 1);
            order[q] = e; keys[q] = k1;
        }
        return;
    }
    __shared__ unsigned short Alds[2][64][32];
    __shared__ unsigned short Blds[2][256][32];
    __shared__ float bias_lds[256];
    int kb = blockIdx.x / NBLK_G;
    int bx = blockIdx.x - kb * NBLK_G;
    const unsigned short* WT; const float* bias; int stride;
    if (kb == 0)      { WT = WTk0;   bias = bk0;   stride = KF_; }
    else if (kb == 1) { WT = WTk1;   bias = bk1;   stride = KF_; }
    else              { WT = WT_lin; bias = b_lin; stride = DIN_; }

    int tid = threadIdx.x;
    int w = tid >> 6, ln = tid & 63, l15 = ln & 15;
    int row0 = bx * 64;
    bias_lds[tid] = bias[tid];

    int ar = row0 + w * 16 + (ln >> 2);
    if (ar >= N_NODES) ar = N_NODES - 1;
    int qs = (ln & 3) ^ ((ln >> 3) & 3);
    const unsigned short* asrc = hbf + (size_t)ar * DIN_ + qs * 8;
    int brow = w * 64;
    int swz = ((ln >> 4) ^ ((l15 >> 1) & 3)) * 8;

    f32x4 acc[16];
#pragma unroll
    for (int j = 0; j < 16; ++j) acc[j] = (f32x4)(0.f);

    gl_lds16(asrc, &Alds[0][w * 16][0]);
#pragma unroll
    for (int i = 0; i < 4; ++i) {
        int n = brow + i * 16 + (ln >> 2);
        gl_lds16(WT + (size_t)n * stride + qs * 8, &Blds[0][brow + i * 16][0]);
    }
    __syncthreads();

    int buf = 0;
    for (int kk = 0; kk < 8; ++kk) {
        if (kk < 7) {
            gl_lds16(asrc + (kk + 1) * 32, &Alds[buf ^ 1][w * 16][0]);
#pragma unroll
            for (int i = 0; i < 4; ++i) {
                int n = brow + i * 16 + (ln >> 2);
                gl_lds16(WT + (size_t)n * stride + (kk + 1) * 32 + qs * 8,
                         &Blds[buf ^ 1][brow + i * 16][0]);
            }
        }
        short8 af = *(const short8*)&Alds[buf][w * 16 + l15][swz];
#pragma unroll
        for (int j = 0; j < 16; ++j) {
            short8 bf = *(const short8*)&Blds[buf][j * 16 + l15][swz];
            acc[j] = __builtin_amdgcn_mfma_f32_16x16x32_bf16(af, bf, acc[j], 0, 0, 0);
        }
        __syncthreads();
        buf ^= 1;
    }

    int rbase = row0 + w * 16 + ((ln >> 4) << 2);
    unsigned short* G = (kb == 0) ? G0 : G1;
#pragma unroll
    for (int j = 0; j < 16; ++j) {
        int n = j * 16 + l15;
        float bv = bias_lds[n];
#pragma unroll
        for (int i = 0; i < 4; ++i) {
            int rr = rbase + i;
            if (rr < N_NODES) {
                float v = acc[j][i] + bv;
                if (kb == 2) out[(size_t)rr * DOUT_ + n] = v;
                else         G[(size_t)rr * DOUT_ + n] = f2bf(v * LOG2E);
            }
        }
    }
}

// Fused edge epilogue v6: exp2-prescaled logits (bare v_exp), fma'd sigmoid product,
// direct coalesced atomics (no LDS flush transpose). Gathers all issued up-front.
__global__ __launch_bounds__(256, 4) void edge_fused(const unsigned short* __restrict__ Gk0,
                                                     const unsigned short* __restrict__ Gk1,
                                                     const int* __restrict__ pairs0,
                                                     const int* __restrict__ pairs1,
                                                     const float* __restrict__ deg0,
                                                     const float* __restrict__ deg1,
                                                     const int* __restrict__ order_all,
                                                     const int* __restrict__ keys_all,
                                                     const unsigned short* __restrict__ WT0,
                                                     const unsigned short* __restrict__ WT1,
                                                     const float* __restrict__ eps0,
                                                     const float* __restrict__ eps1,
                                                     float* __restrict__ out) {
    __shared__ unsigned int Dlds[4][16][132];   // per-wave D slice (t-packed), 33.8 KB
    __shared__ int tgt[64], pl0[64], pl1[64], el[64];
    int kb = (blockIdx.x >= NBLK_EDGE) ? 1 : 0;
    int bx = blockIdx.x - kb * NBLK_EDGE;
    const unsigned short* G = kb ? Gk1 : Gk0;
    const int* pairs = kb ? pairs1 : pairs0;
    const float* degrees = kb ? deg1 : deg0;
    const int* order_k = order_all + kb * N_EDGES;
    const int* keys_k  = keys_all + kb * N_EDGES;
    const unsigned short* WT = kb ? WT1 : WT0;
    float epv = 1.0f + (kb ? eps1[0] : eps0[0]);

    int tid = threadIdx.x;
    int w = tid >> 6, ln = tid & 63, l15 = ln & 15, ks = ln >> 4;
    int e0 = bx * 64;
    if (tid < 64) {
        int s = e0 + tid;
        int sc = (s < N_EDGES) ? s : N_EDGES - 1;
        int e = __builtin_nontemporal_load(order_k + sc);
        el[tid]  = e;
        tgt[tid] = (s < N_EDGES) ? __builtin_nontemporal_load(keys_k + s) : -1;
        pl0[tid] = __builtin_nontemporal_load(pairs + e);
        pl1[tid] = __builtin_nontemporal_load(pairs + N_EDGES + e);
    }
    __syncthreads();   // the only block barrier

    // ---- degrees loads (oldest in flight) ----
    int eA = el[w * 16 + l15];
    f32x4 xa = (f32x4)(0.f), xb = xa, ya = xa, yb = xa;
    if (ks < 2) {
        const f32x4* s0 = (const f32x4*)(degrees + (size_t)eA * OH_ + ks * 8);
        const f32x4* s1 = (const f32x4*)(degrees + ((size_t)N_EDGES + eA) * OH_ + ks * 8);
        xa = __builtin_nontemporal_load(s0);
        xb = __builtin_nontemporal_load(s0 + 1);
        ya = __builtin_nontemporal_load(s1);
        yb = __builtin_nontemporal_load(s1 + 1);
    }

    // ---- ALL 64 gather dwords issued here, kept in flight ----
    unsigned int gv[4][16];
#pragma unroll
    for (int r2 = 0; r2 < 16; ++r2) {
        int row = w * 16 + r2;
        const unsigned int* b0 = (const unsigned int*)(G + (size_t)pl0[row] * DOUT_) + ln;
        const unsigned int* b1 = (const unsigned int*)(G + (size_t)pl1[row] * DOUT_) + ln;
        gv[0][r2] = b0[0];
        gv[1][r2] = b1[0];
        gv[2][r2] = b0[64];
        gv[3][r2] = b1[64];
    }
    asm volatile("" ::: "memory");   // pin: loads above issue before anything below

    short8 a0f = __builtin_bit_cast(short8, pack8(xa[0], xa[1], xa[2], xa[3],
                                                  xb[0], xb[1], xb[2], xb[3]));
    short8 a1f = __builtin_bit_cast(short8, pack8(ya[0], ya[1], ya[2], ya[3],
                                                  yb[0], yb[1], yb[2], yb[3]));
    if (ks >= 2) { a0f = (short8)0; a1f = (short8)0; }

#define MFMA_PHASE(p)                                                                  \
    {                                                                                  \
        f32x4 acc0[8], acc1[8];                                                        \
        _Pragma("unroll")                                                              \
        for (int j = 0; j < 8; ++j) { acc0[j] = (f32x4)(0.f); acc1[j] = (f32x4)(0.f); }\
        _Pragma("unroll")                                                              \
        for (int j = 0; j < 8; ++j) {                                                  \
            int n = (p) * 128 + j * 16 + l15;                                          \
            short8 bf = (short8)0;                                                     \
            if (ks < 2) bf = *(const short8*)(WT + (size_t)n * KF_ + 256 + ks * 8);    \
            acc0[j] = __builtin_amdgcn_mfma_f32_16x16x32_bf16(a0f, bf, acc0[j], 0,0,0);\
            acc1[j] = __builtin_amdgcn_mfma_f32_16x16x32_bf16(a1f, bf, acc1[j], 0,0,0);\
        }                                                                              \
        _Pragma("unroll")                                                              \
        for (int j = 0; j < 8; ++j) {                                                  \
            _Pragma("unroll")                                                          \
            for (int i = 0; i < 4; ++i) {                                              \
                Dlds[w][ks * 4 + i][j * 16 + l15] = (unsigned)f2bf(acc0[j][i])         \
                                                  | ((unsigned)f2bf(acc1[j][i]) << 16);\
            }                                                                          \
        }                                                                              \
    }

#define REDUCE_PHASE(p, gva, gvb)                                                      \
    {                                                                                  \
        int runkey = tgt[w * 16];                                                      \
        float rs0 = 0.f, rs1 = 0.f;                                                    \
        _Pragma("unroll")                                                              \
        for (int r2 = 0; r2 < 16; ++r2) {                                              \
            int row = w * 16 + r2;                                                     \
            uint2 dp = *(const uint2*)&Dlds[w][r2][2 * ln];                            \
            unsigned int g0u = (gva)[r2], g1u = (gvb)[r2];                             \
            float la0 = bf2f(g0u & 0xffffu) + bf2f(dp.x & 0xffffu);                    \
            float la1 = bf2f(g1u & 0xffffu) + bf2f(dp.x >> 16);                        \
            float ha0 = bf2f(g0u >> 16) + bf2f(dp.y & 0xffffu);                        \
            float ha1 = bf2f(g1u >> 16) + bf2f(dp.y >> 16);                            \
            float ea0 = fast_exp2(-la0), ea1 = fast_exp2(-la1);                        \
            float eb0 = fast_exp2(-ha0), eb1 = fast_exp2(-ha1);                        \
            float u0 = 1.f + ea0, u1 = 1.f + eb0;                                      \
            float v0 = fast_rcp(__builtin_fmaf(u0, ea1, u0));                          \
            float v1 = fast_rcp(__builtin_fmaf(u1, eb1, u1));                          \
            int k = tgt[row];                                                          \
            if (k != runkey) {                                                         \
                if (runkey >= 0) {                                                     \
                    atomicAdd(&out[(size_t)runkey * DOUT_ + (p) * 128 + 2 * ln],       \
                              epv * rs0);                                              \
                    atomicAdd(&out[(size_t)runkey * DOUT_ + (p) * 128 + 2 * ln + 1],   \
                              epv * rs1);                                              \
                }                                                                      \
                runkey = k; rs0 = v0; rs1 = v1;                                        \
            } else { rs0 += v0; rs1 += v1; }                                           \
        }                                                                              \
        if (runkey >= 0) {                                                             \
            atomicAdd(&out[(size_t)runkey * DOUT_ + (p) * 128 + 2 * ln], epv * rs0);   \
            atomicAdd(&out[(size_t)runkey * DOUT_ + (p) * 128 + 2 * ln + 1],           \
                      epv * rs1);                                                      \
        }                                                                              \
    }

    MFMA_PHASE(0);
    REDUCE_PHASE(0, gv[0], gv[1]);
    MFMA_PHASE(1);
    REDUCE_PHASE(1, gv[2], gv[3]);

#undef MFMA_PHASE
#undef REDUCE_PHASE
}

extern "C" void kernel_launch(void* const* d_in, const int* in_sizes, int n_in,
                              void* d_out, int out_size, void* d_ws, size_t ws_size,
                              hipStream_t stream) {
    const float* h        = (const float*)d_in[0];
    const int*   pairs_k0 = (const int*)d_in[1];
    const int*   pairs_k1 = (const int*)d_in[2];
    const float* deg_k0   = (const float*)d_in[3];
    const float* deg_k1   = (const float*)d_in[4];
    const int*   sc_k0    = (const int*)d_in[5];
    const int*   sc_k1    = (const int*)d_in[6];
    const float* W_lin    = (const float*)d_in[7];
    const float* b_lin    = (const float*)d_in[8];
    const float* W_k0     = (const float*)d_in[9];
    const float* b_k0     = (const float*)d_in[10];
    const float* W_k1     = (const float*)d_in[11];
    const float* b_k1     = (const float*)d_in[12];
    const float* eps_k0   = (const float*)d_in[13];
    const float* eps_k1   = (const float*)d_in[14];
    float* out = (float*)d_out;

    size_t ush_elems = (size_t)DOUT_ * DIN_ + 2 * (size_t)DOUT_ * KF_
                     + 3 * (size_t)N_NODES * DIN_;          // h_bf + G0 + G1
    size_t int_elems = 2 * (size_t)N_NODES * 2 + 2 * (size_t)N_EDGES * 2 + 512;
    size_t need = ush_elems * sizeof(unsigned short) + int_elems * sizeof(int);
    if (ws_size < need) return;  // fail loudly in validation

    unsigned short* WT_lin = (unsigned short*)d_ws;
    unsigned short* WT_k0  = WT_lin + DOUT_ * DIN_;
    unsigned short* WT_k1  = WT_k0 + DOUT_ * KF_;
    unsigned short* h_bf   = WT_k1 + DOUT_ * KF_;
    unsigned short* G0     = h_bf + (size_t)N_NODES * DIN_;
    unsigned short* G1     = G0 + (size_t)N_NODES * DIN_;
    int* hist     = (int*)(G1 + (size_t)N_NODES * DIN_);
    int* offs     = hist + 2 * N_NODES;
    int* order    = offs + 2 * N_NODES;     // [2*E]
    int* keys     = order + 2 * N_EDGES;    // [2*E]
    int* partials = keys + 2 * N_EDGES;     // [512]

    hipMemsetAsync(hist, 0, 2 * N_NODES * sizeof(int), stream);
    fused_prep<<<NB_CONV + NB_PREP + NB_HIST, 256, 0, stream>>>(
        h, h_bf, W_lin, W_k0, W_k1, WT_lin, WT_k0, WT_k1, sc_k0, sc_k1, hist);
    scan_pass1<<<SCAN_NB, 256, 0, stream>>>(hist, partials);
    scan_pass2<<<1, 512, 0, stream>>>(partials);
    scan_pass3<<<SCAN_NB, 256, 0, stream>>>(hist, partials, offs);
    rank_lin<<<3 * NBLK_G + NB_HIST, 256, 0, stream>>>(
        sc_k0, sc_k1, offs, order, keys, h_bf, WT_lin, WT_k0, WT_k1,
        b_lin, b_k0, b_k1, out, G0, G1);
    edge_fused<<<2 * NBLK_EDGE, 256, 0, stream>>>(G0, G1, pairs_k0, pairs_k1,
                                                  deg_k0, deg_k1, order, keys,
                                                  WT_k0, WT_k1, eps_k0, eps_k1, out);
}

// Round 14
// 368.497 us; speedup vs baseline: 1.2614x; 1.1530x over previous
//
#include <hip/hip_runtime.h>
#include <hip/hip_bf16.h>

#define N_NODES 50000
#define N_EDGES 250000
#define DIN_ 256
#define DOUT_ 256
#define OH_ 16
#define KF_ 288   // 256 (h) + 16 (degrees) + 16 zero-pad
#define NBLK_EDGE ((N_EDGES + 63) / 64)     // 3907
#define NBLK_G ((N_NODES + 63) / 64)        // 782
#define SCAN_TOT (2 * N_NODES)              // 100000
#define SCAN_NB ((SCAN_TOT + 255) / 256)    // 391
#define NB_CONV ((N_NODES * DIN_ / 8) / 256)        // 6250
#define NB_PREP ((DOUT_ * KF_ + 255) / 256)         // 288
#define NB_HIST ((N_EDGES + 255) / 256)             // 977
#define LOG2E 1.44269504088896340736f

typedef short short8 __attribute__((ext_vector_type(8)));
typedef float f32x4 __attribute__((ext_vector_type(4)));

__device__ __forceinline__ unsigned short f2bf(float f) {
    unsigned u = __builtin_bit_cast(unsigned, f);
    return (unsigned short)((u + 0x7fffu + ((u >> 16) & 1u)) >> 16);
}

__device__ __forceinline__ float bf2f(unsigned v) {
    return __builtin_bit_cast(float, v << 16);
}

__device__ __forceinline__ uint4 pack8(float f0, float f1, float f2, float f3,
                                       float f4, float f5, float f6, float f7) {
    uint4 u;
    u.x = (unsigned)f2bf(f0) | ((unsigned)f2bf(f1) << 16);
    u.y = (unsigned)f2bf(f2) | ((unsigned)f2bf(f3) << 16);
    u.z = (unsigned)f2bf(f4) | ((unsigned)f2bf(f5) << 16);
    u.w = (unsigned)f2bf(f6) | ((unsigned)f2bf(f7) << 16);
    return u;
}

__device__ __forceinline__ float fast_rcp(float x) {
#if __has_builtin(__builtin_amdgcn_rcpf)
    return __builtin_amdgcn_rcpf(x);
#else
    return 1.0f / x;
#endif
}

__device__ __forceinline__ float fast_exp2(float x) {
#if __has_builtin(__builtin_amdgcn_exp2f)
    return __builtin_amdgcn_exp2f(x);
#else
    return exp2f(x);
#endif
}

// async global -> LDS, 16 bytes per lane (dest = wave-uniform base + lane*16)
__device__ __forceinline__ void gl_lds16(const void* g, void* l) {
    __builtin_amdgcn_global_load_lds(
        (const __attribute__((address_space(1))) unsigned int*)g,
        (__attribute__((address_space(3))) unsigned int*)l, 16, 0, 0);
}

// ---------- fused prep: conv_h + prep_weights + hist ----------
// Deg-weight rows (k >= 256) pre-scaled by log2(e) so edge logits are exp2-ready.
__global__ void fused_prep(const float* __restrict__ h, unsigned short* __restrict__ hbf,
                           const float* __restrict__ W_lin,
                           const float* __restrict__ W_k0,
                           const float* __restrict__ W_k1,
                           unsigned short* __restrict__ WT_lin,
                           unsigned short* __restrict__ WT_k0,
                           unsigned short* __restrict__ WT_k1,
                           const int* __restrict__ sc0, const int* __restrict__ sc1,
                           int* __restrict__ hist) {
    int bx = blockIdx.x;
    if (bx < NB_CONV) {
        int idx = bx * 256 + threadIdx.x;
        const f32x4* s = (const f32x4*)(h + (size_t)idx * 8);
        f32x4 a = s[0], b = s[1];
        ((uint4*)hbf)[idx] = pack8(a[0], a[1], a[2], a[3], b[0], b[1], b[2], b[3]);
    } else if (bx < NB_CONV + NB_PREP) {
        int idx = (bx - NB_CONV) * 256 + threadIdx.x;
        if (idx < DOUT_ * DIN_) {
            int n = idx >> 8, k = idx & 255;
            WT_lin[idx] = f2bf(W_lin[k * DOUT_ + n]);
        }
        if (idx < DOUT_ * KF_) {
            int n = idx / KF_, k = idx - n * KF_;
            float v0 = 0.f, v1 = 0.f;
            if (k < DIN_ + OH_) {
                v0 = W_k0[k * DOUT_ + n];
                v1 = W_k1[k * DOUT_ + n];
                if (k >= DIN_) { v0 *= LOG2E; v1 *= LOG2E; }   // deg rows exp2-scaled
            }
            WT_k0[idx] = f2bf(v0);
            WT_k1[idx] = f2bf(v1);
        }
    } else {
        int e = (bx - NB_CONV - NB_PREP) * 256 + threadIdx.x;
        if (e < N_EDGES) {
            atomicAdd(&hist[sc0[e]], 1);
            atomicAdd(&hist[N_NODES + sc1[e]], 1);
        }
    }
}

// ---------- scan passes ----------
__global__ void scan_pass1(const int* __restrict__ hist, int* __restrict__ partials) {
    __shared__ int sdata[256];
    int gid = blockIdx.x * 256 + threadIdx.x;
    sdata[threadIdx.x] = (gid < SCAN_TOT) ? hist[gid] : 0;
    __syncthreads();
    for (int d = 128; d > 0; d >>= 1) {
        if (threadIdx.x < d) sdata[threadIdx.x] += sdata[threadIdx.x + d];
        __syncthreads();
    }
    if (threadIdx.x == 0) partials[blockIdx.x] = sdata[0];
}

__global__ __launch_bounds__(512) void scan_pass2(int* __restrict__ partials) {
    __shared__ int s[512];
    int t = threadIdx.x;
    s[t] = (t < SCAN_NB) ? partials[t] : 0;
    __syncthreads();
    for (int d = 1; d < 512; d <<= 1) {
        int add = (t >= d) ? s[t - d] : 0;
        __syncthreads();
        s[t] += add;
        __syncthreads();
    }
    if (t < SCAN_NB) partials[t] = (t == 0) ? 0 : s[t - 1];   // exclusive
}

__global__ void scan_pass3(const int* __restrict__ hist, const int* __restrict__ partials,
                           int* __restrict__ offs) {
    __shared__ int s[256];
    int gid = blockIdx.x * 256 + threadIdx.x;
    int t = threadIdx.x;
    int v = (gid < SCAN_TOT) ? hist[gid] : 0;
    s[t] = v;
    __syncthreads();
    for (int d = 1; d < 256; d <<= 1) {
        int add = (t >= d) ? s[t - d] : 0;
        __syncthreads();
        s[t] += add;
        __syncthreads();
    }
    if (gid < SCAN_TOT) offs[gid] = partials[blockIdx.x] + s[t] - v;  // exclusive
}

// ---------- fused: rank + 3 linear GEMMs ----------
// G epilogue pre-scales by log2(e) (bias folded first) for the exp2 edge path.
__global__ __launch_bounds__(256) void rank_lin(const int* __restrict__ sc0,
                                                const int* __restrict__ sc1,
                                                int* __restrict__ offs,
                                                int* __restrict__ order,
                                                int* __restrict__ keys,
                                                const unsigned short* __restrict__ hbf,
                                                const unsigned short* __restrict__ WT_lin,
                                                const unsigned short* __restrict__ WTk0,
                                                const unsigned short* __restrict__ WTk1,
                                                const float* __restrict__ b_lin,
                                                const float* __restrict__ bk0,
                                                const float* __restrict__ bk1,
                                                float* __restrict__ out,
                                                unsigned short* __restrict__ G0,
                                                unsigned short* __restrict__ G1) {
    if (blockIdx.x >= 3 * NBLK_G) {
        int e = (blockIdx.x - 3 * NBLK_G) * 256 + threadIdx.x;
        if (e < N_EDGES) {
            int k0 = sc0[e];
            int p = atomicAdd(&offs[k0], 1);
            order[p] = e; keys[p] = k0;
            int k1 = sc1[e];
            int q = atomicAdd(&offs[N_NODES + k1], 1);
            order[q] = e; keys[q] = k1;
        }
        return;
    }
    __shared__ unsigned short Alds[2][64][32];
    __shared__ unsigned short Blds[2][256][32];
    __shared__ float bias_lds[256];
    int kb = blockIdx.x / NBLK_G;
    int bx = blockIdx.x - kb * NBLK_G;
    const unsigned short* WT; const float* bias; int stride;
    if (kb == 0)      { WT = WTk0;   bias = bk0;   stride = KF_; }
    else if (kb == 1) { WT = WTk1;   bias = bk1;   stride = KF_; }
    else              { WT = WT_lin; bias = b_lin; stride = DIN_; }

    int tid = threadIdx.x;
    int w = tid >> 6, ln = tid & 63, l15 = ln & 15;
    int row0 = bx * 64;
    bias_lds[tid] = bias[tid];

    int ar = row0 + w * 16 + (ln >> 2);
    if (ar >= N_NODES) ar = N_NODES - 1;
    int qs = (ln & 3) ^ ((ln >> 3) & 3);
    const unsigned short* asrc = hbf + (size_t)ar * DIN_ + qs * 8;
    int brow = w * 64;
    int swz = ((ln >> 4) ^ ((l15 >> 1) & 3)) * 8;

    f32x4 acc[16];
#pragma unroll
    for (int j = 0; j < 16; ++j) acc[j] = (f32x4)(0.f);

    gl_lds16(asrc, &Alds[0][w * 16][0]);
#pragma unroll
    for (int i = 0; i < 4; ++i) {
        int n = brow + i * 16 + (ln >> 2);
        gl_lds16(WT + (size_t)n * stride + qs * 8, &Blds[0][brow + i * 16][0]);
    }
    __syncthreads();

    int buf = 0;
    for (int kk = 0; kk < 8; ++kk) {
        if (kk < 7) {
            gl_lds16(asrc + (kk + 1) * 32, &Alds[buf ^ 1][w * 16][0]);
#pragma unroll
            for (int i = 0; i < 4; ++i) {
                int n = brow + i * 16 + (ln >> 2);
                gl_lds16(WT + (size_t)n * stride + (kk + 1) * 32 + qs * 8,
                         &Blds[buf ^ 1][brow + i * 16][0]);
            }
        }
        short8 af = *(const short8*)&Alds[buf][w * 16 + l15][swz];
#pragma unroll
        for (int j = 0; j < 16; ++j) {
            short8 bf = *(const short8*)&Blds[buf][j * 16 + l15][swz];
            acc[j] = __builtin_amdgcn_mfma_f32_16x16x32_bf16(af, bf, acc[j], 0, 0, 0);
        }
        __syncthreads();
        buf ^= 1;
    }

    int rbase = row0 + w * 16 + ((ln >> 4) << 2);
    unsigned short* G = (kb == 0) ? G0 : G1;
#pragma unroll
    for (int j = 0; j < 16; ++j) {
        int n = j * 16 + l15;
        float bv = bias_lds[n];
#pragma unroll
        for (int i = 0; i < 4; ++i) {
            int rr = rbase + i;
            if (rr < N_NODES) {
                float v = acc[j][i] + bv;
                if (kb == 2) out[(size_t)rr * DOUT_ + n] = v;
                else         G[(size_t)rr * DOUT_ + n] = f2bf(v * LOG2E);
            }
        }
    }
}

// Fused edge epilogue v7: exp2-prescaled logits + restored FL flush-transpose
// (unit-stride 256B atomic instructions). Gathers all issued up-front.
__global__ __launch_bounds__(256, 4) void edge_fused(const unsigned short* __restrict__ Gk0,
                                                     const unsigned short* __restrict__ Gk1,
                                                     const int* __restrict__ pairs0,
                                                     const int* __restrict__ pairs1,
                                                     const float* __restrict__ deg0,
                                                     const float* __restrict__ deg1,
                                                     const int* __restrict__ order_all,
                                                     const int* __restrict__ keys_all,
                                                     const unsigned short* __restrict__ WT0,
                                                     const unsigned short* __restrict__ WT1,
                                                     const float* __restrict__ eps0,
                                                     const float* __restrict__ eps1,
                                                     float* __restrict__ out) {
    __shared__ unsigned int Dlds[4][16][132];   // per-wave D slice (t-packed), 33.8 KB
    __shared__ float FL[4][64][2];              // per-wave flush transpose, 2 KB
    __shared__ int tgt[64], pl0[64], pl1[64], el[64];
    int kb = (blockIdx.x >= NBLK_EDGE) ? 1 : 0;
    int bx = blockIdx.x - kb * NBLK_EDGE;
    const unsigned short* G = kb ? Gk1 : Gk0;
    const int* pairs = kb ? pairs1 : pairs0;
    const float* degrees = kb ? deg1 : deg0;
    const int* order_k = order_all + kb * N_EDGES;
    const int* keys_k  = keys_all + kb * N_EDGES;
    const unsigned short* WT = kb ? WT1 : WT0;
    float epv = 1.0f + (kb ? eps1[0] : eps0[0]);

    int tid = threadIdx.x;
    int w = tid >> 6, ln = tid & 63, l15 = ln & 15, ks = ln >> 4;
    int e0 = bx * 64;
    if (tid < 64) {
        int s = e0 + tid;
        int sc = (s < N_EDGES) ? s : N_EDGES - 1;
        int e = __builtin_nontemporal_load(order_k + sc);
        el[tid]  = e;
        tgt[tid] = (s < N_EDGES) ? __builtin_nontemporal_load(keys_k + s) : -1;
        pl0[tid] = __builtin_nontemporal_load(pairs + e);
        pl1[tid] = __builtin_nontemporal_load(pairs + N_EDGES + e);
    }
    __syncthreads();   // the only block barrier

    // ---- degrees loads (oldest in flight) ----
    int eA = el[w * 16 + l15];
    f32x4 xa = (f32x4)(0.f), xb = xa, ya = xa, yb = xa;
    if (ks < 2) {
        const f32x4* s0 = (const f32x4*)(degrees + (size_t)eA * OH_ + ks * 8);
        const f32x4* s1 = (const f32x4*)(degrees + ((size_t)N_EDGES + eA) * OH_ + ks * 8);
        xa = __builtin_nontemporal_load(s0);
        xb = __builtin_nontemporal_load(s0 + 1);
        ya = __builtin_nontemporal_load(s1);
        yb = __builtin_nontemporal_load(s1 + 1);
    }

    // ---- ALL 64 gather dwords issued here, kept in flight ----
    unsigned int gv[4][16];
#pragma unroll
    for (int r2 = 0; r2 < 16; ++r2) {
        int row = w * 16 + r2;
        const unsigned int* b0 = (const unsigned int*)(G + (size_t)pl0[row] * DOUT_) + ln;
        const unsigned int* b1 = (const unsigned int*)(G + (size_t)pl1[row] * DOUT_) + ln;
        gv[0][r2] = b0[0];
        gv[1][r2] = b1[0];
        gv[2][r2] = b0[64];
        gv[3][r2] = b1[64];
    }
    asm volatile("" ::: "memory");   // pin: loads above issue before anything below

    short8 a0f = __builtin_bit_cast(short8, pack8(xa[0], xa[1], xa[2], xa[3],
                                                  xb[0], xb[1], xb[2], xb[3]));
    short8 a1f = __builtin_bit_cast(short8, pack8(ya[0], ya[1], ya[2], ya[3],
                                                  yb[0], yb[1], yb[2], yb[3]));
    if (ks >= 2) { a0f = (short8)0; a1f = (short8)0; }

#define MFMA_PHASE(p)                                                                  \
    {                                                                                  \
        f32x4 acc0[8], acc1[8];                                                        \
        _Pragma("unroll")                                                              \
        for (int j = 0; j < 8; ++j) { acc0[j] = (f32x4)(0.f); acc1[j] = (f32x4)(0.f); }\
        _Pragma("unroll")                                                              \
        for (int j = 0; j < 8; ++j) {                                                  \
            int n = (p) * 128 + j * 16 + l15;                                          \
            short8 bf = (short8)0;                                                     \
            if (ks < 2) bf = *(const short8*)(WT + (size_t)n * KF_ + 256 + ks * 8);    \
            acc0[j] = __builtin_amdgcn_mfma_f32_16x16x32_bf16(a0f, bf, acc0[j], 0,0,0);\
            acc1[j] = __builtin_amdgcn_mfma_f32_16x16x32_bf16(a1f, bf, acc1[j], 0,0,0);\
        }                                                                              \
        _Pragma("unroll")                                                              \
        for (int j = 0; j < 8; ++j) {                                                  \
            _Pragma("unroll")                                                          \
            for (int i = 0; i < 4; ++i) {                                              \
                Dlds[w][ks * 4 + i][j * 16 + l15] = (unsigned)f2bf(acc0[j][i])         \
                                                  | ((unsigned)f2bf(acc1[j][i]) << 16);\
            }                                                                          \
        }                                                                              \
    }

#define FLUSH(p, key, r0, r1)                                                          \
    if ((key) >= 0) {                                                                  \
        FL[w][ln][0] = (r0);                                                           \
        FL[w][ln][1] = (r1);                                                           \
        float va = FL[w][(ln >> 1)][ln & 1];                                           \
        float vb = FL[w][32 + (ln >> 1)][ln & 1];                                      \
        atomicAdd(&out[(size_t)(key) * DOUT_ + (p) * 128 + ln], epv * va);             \
        atomicAdd(&out[(size_t)(key) * DOUT_ + (p) * 128 + 64 + ln], epv * vb);        \
    }

#define REDUCE_PHASE(p, gva, gvb)                                                      \
    {                                                                                  \
        int runkey = tgt[w * 16];                                                      \
        float rs0 = 0.f, rs1 = 0.f;                                                    \
        _Pragma("unroll")                                                              \
        for (int r2 = 0; r2 < 16; ++r2) {                                              \
            int row = w * 16 + r2;                                                     \
            uint2 dp = *(const uint2*)&Dlds[w][r2][2 * ln];                            \
            unsigned int g0u = (gva)[r2], g1u = (gvb)[r2];                             \
            float la0 = bf2f(g0u & 0xffffu) + bf2f(dp.x & 0xffffu);                    \
            float la1 = bf2f(g1u & 0xffffu) + bf2f(dp.x >> 16);                        \
            float ha0 = bf2f(g0u >> 16) + bf2f(dp.y & 0xffffu);                        \
            float ha1 = bf2f(g1u >> 16) + bf2f(dp.y >> 16);                            \
            float ea0 = fast_exp2(-la0), ea1 = fast_exp2(-la1);                        \
            float eb0 = fast_exp2(-ha0), eb1 = fast_exp2(-ha1);                        \
            float u0 = 1.f + ea0, u1 = 1.f + eb0;                                      \
            float v0 = fast_rcp(__builtin_fmaf(u0, ea1, u0));                          \
            float v1 = fast_rcp(__builtin_fmaf(u1, eb1, u1));                          \
            int k = tgt[row];                                                          \
            if (k != runkey) {                                                         \
                FLUSH(p, runkey, rs0, rs1);                                            \
                runkey = k; rs0 = v0; rs1 = v1;                                        \
            } else { rs0 += v0; rs1 += v1; }                                           \
        }                                                                              \
        FLUSH(p, runkey, rs0, rs1);                                                    \
    }

    MFMA_PHASE(0);
    REDUCE_PHASE(0, gv[0], gv[1]);
    MFMA_PHASE(1);
    REDUCE_PHASE(1, gv[2], gv[3]);

#undef MFMA_PHASE
#undef FLUSH
#undef REDUCE_PHASE
}

extern "C" void kernel_launch(void* const* d_in, const int* in_sizes, int n_in,
                              void* d_out, int out_size, void* d_ws, size_t ws_size,
                              hipStream_t stream) {
    const float* h        = (const float*)d_in[0];
    const int*   pairs_k0 = (const int*)d_in[1];
    const int*   pairs_k1 = (const int*)d_in[2];
    const float* deg_k0   = (const float*)d_in[3];
    const float* deg_k1   = (const float*)d_in[4];
    const int*   sc_k0    = (const int*)d_in[5];
    const int*   sc_k1    = (const int*)d_in[6];
    const float* W_lin    = (const float*)d_in[7];
    const float* b_lin    = (const float*)d_in[8];
    const float* W_k0     = (const float*)d_in[9];
    const float* b_k0     = (const float*)d_in[10];
    const float* W_k1     = (const float*)d_in[11];
    const float* b_k1     = (const float*)d_in[12];
    const float* eps_k0   = (const float*)d_in[13];
    const float* eps_k1   = (const float*)d_in[14];
    float* out = (float*)d_out;

    size_t ush_elems = (size_t)DOUT_ * DIN_ + 2 * (size_t)DOUT_ * KF_
                     + 3 * (size_t)N_NODES * DIN_;          // h_bf + G0 + G1
    size_t int_elems = 2 * (size_t)N_NODES * 2 + 2 * (size_t)N_EDGES * 2 + 512;
    size_t need = ush_elems * sizeof(unsigned short) + int_elems * sizeof(int);
    if (ws_size < need) return;  // fail loudly in validation

    unsigned short* WT_lin = (unsigned short*)d_ws;
    unsigned short* WT_k0  = WT_lin + DOUT_ * DIN_;
    unsigned short* WT_k1  = WT_k0 + DOUT_ * KF_;
    unsigned short* h_bf   = WT_k1 + DOUT_ * KF_;
    unsigned short* G0     = h_bf + (size_t)N_NODES * DIN_;
    unsigned short* G1     = G0 + (size_t)N_NODES * DIN_;
    int* hist     = (int*)(G1 + (size_t)N_NODES * DIN_);
    int* offs     = hist + 2 * N_NODES;
    int* order    = offs + 2 * N_NODES;     // [2*E]
    int* keys     = order + 2 * N_EDGES;    // [2*E]
    int* partials = keys + 2 * N_EDGES;     // [512]

    hipMemsetAsync(hist, 0, 2 * N_NODES * sizeof(int), stream);
    fused_prep<<<NB_CONV + NB_PREP + NB_HIST, 256, 0, stream>>>(
        h, h_bf, W_lin, W_k0, W_k1, WT_lin, WT_k0, WT_k1, sc_k0, sc_k1, hist);
    scan_pass1<<<SCAN_NB, 256, 0, stream>>>(hist, partials);
    scan_pass2<<<1, 512, 0, stream>>>(partials);
    scan_pass3<<<SCAN_NB, 256, 0, stream>>>(hist, partials, offs);
    rank_lin<<<3 * NBLK_G + NB_HIST, 256, 0, stream>>>(
        sc_k0, sc_k1, offs, order, keys, h_bf, WT_lin, WT_k0, WT_k1,
        b_lin, b_k0, b_k1, out, G0, G1);
    edge_fused<<<2 * NBLK_EDGE, 256, 0, stream>>>(G0, G1, pairs_k0, pairs_k1,
                                                  deg_k0, deg_k1, order, keys,
                                                  WT_k0, WT_k1, eps_k0, eps_k1, out);
}